// Round 7
// baseline (136.268 us; speedup 1.0000x reference)
//
#include <hip/hip_runtime.h>
#include <hip/hip_bf16.h>

// FLDAttention — single kernel, no grid barriers, no global scratch.
//
// Algebra:
//   scores are channel-independent; mask enters as 0/1 weights; with
//   x = num/den the softmax row-max cancels (scores ~N(0,0.08), exp safe):
//     e[h,q,k] = exp((key[k,:]·u[h,q,:] + beta[h,q]) / 4)
//     u[h,q,t] = sum_c Wk[t, h*16+c] * qproj[q, h*16+c]   (k-projection folded
//     beta[h,q] = sum_c bk[h*16+c]  * qproj[q, h*16+c]     into the q side!)
//     x[h,q,c] = (sum_k e*m[k,c]*v[k,c]) / (sum_k e*m[k,c])
//
// Schedule (this round): value/mask loads are register-prefetched one chunk
// ahead (issued BEFORE the barrier, consumed after the next one) so L2
// latency hides under a full chunk of FMA work; chunk-0 loads are issued at
// kernel entry under the prologue; score work alternates between wave-halves
// (even chunks: waves 0-3, odd: waves 4-7) to balance per-barrier load.
//
// Block = (b = blk&7, 2 q-rows). 512 threads (8 waves). 256 blocks = 1/CU.

#define NBLK 256

__global__ __launch_bounds__(512) void fld_fused(
    const float* __restrict__ query, const float* __restrict__ key,
    const float* __restrict__ value, const int* __restrict__ mask,
    const float* __restrict__ Wq, const float* __restrict__ bq,
    const float* __restrict__ Wk, const float* __restrict__ bk,
    const float* __restrict__ Wout, const float* __restrict__ bout,
    float* __restrict__ out) {
  __shared__ float q_l[2 * 36];            // projected q rows
  __shared__ float u_l[4 * 36];            // folded score vectors [row][32]
  __shared__ float beta_l[4];
  __shared__ float e_t[2][64 * 4];         // [buf][k][row] exp(scores), transposed
  __shared__ float red_n[4 * 8 * 32 * 4];  // [row][w][cq][4ch] partial numerators
  __shared__ float red_d[4 * 8 * 32 * 4];  // partial denominators
  __shared__ float x_l[2 * 264];           // [q][h*128+c]
  __shared__ float p4[64 * 64];            // [g*2+q][oc] out-GEMM partials

  const int tid = threadIdx.x;
  const int blk = blockIdx.x;
  const int b = blk & 7;
  const int q0 = (blk >> 3) * 2;

  const int w = tid >> 6, kkl = (tid >> 5) & 1, cq = tid & 31;
  const int kb = w * 2 + kkl;
  const int row4 = (tid >> 6) & 3;         // score row for this thread
  const float4* value4 = (const float4*)value;
  const int4* mask4 = (const int4*)mask;

  auto issue = [&](int kc, float4 (&pv)[4], int4 (&pm)[4]) {
#pragma unroll
    for (int j = 0; j < 4; ++j) {
      const int kk = kb + j * 16;
      const size_t g = (size_t)(b * 512 + kc * 64 + kk) * 32 + cq;
      pv[j] = value4[g];
      pm[j] = mask4[g];
    }
  };

  // chunk-0 loads in flight under the whole prologue
  float4 pv0[4], pv1[4];
  int4 pm0[4], pm1[4];
  issue(0, pv0, pm0);

  // ---- prologue: q projection (row encoding: row = h*2 + q) ----
  if (tid < 64) {
    const int q = tid >> 5, c = tid & 31;
    const float* qrow = query + (size_t)(b * 64 + q0 + q) * 32;
    float acc = bq[c];
#pragma unroll
    for (int t = 0; t < 32; ++t) acc += qrow[t] * Wq[t * 32 + c];
    q_l[q * 36 + c] = acc;
  }
  __syncthreads();
  if (tid < 128) {
    const int row = tid >> 5, t = tid & 31;
    const int h = row >> 1, q = row & 1;
    float acc = 0.f;
#pragma unroll
    for (int c = 0; c < 16; ++c)
      acc += Wk[t * 32 + h * 16 + c] * q_l[q * 36 + h * 16 + c];
    u_l[row * 36 + t] = acc;
  } else if (tid < 132) {
    const int row = tid - 128;
    const int h = row >> 1, q = row & 1;
    float acc = 0.f;
#pragma unroll
    for (int c = 0; c < 16; ++c) acc += bk[h * 16 + c] * q_l[q * 36 + h * 16 + c];
    beta_l[row] = acc;
  }
  __syncthreads();

  // ---- all threads hold u for their row in registers ----
  float u_reg[32];
#pragma unroll
  for (int i = 0; i < 8; ++i) {
    float4 v = *(const float4*)&u_l[row4 * 36 + i * 4];
    u_reg[i * 4 + 0] = v.x; u_reg[i * 4 + 1] = v.y;
    u_reg[i * 4 + 2] = v.z; u_reg[i * 4 + 3] = v.w;
  }
  const float beta_reg = beta_l[row4];

  // scores for chunk kc: even -> waves 0-3 (tid<256), odd -> waves 4-7
  auto do_scores = [&](int kc) {
    if ((tid >> 8) == (kc & 1)) {
      const int k = tid & 63;
      const float* krow = key + (size_t)(b * 512 + kc * 64 + k) * 32;
      float acc = beta_reg;
#pragma unroll
      for (int i = 0; i < 8; ++i) {
        float4 v = *(const float4*)&krow[i * 4];
        acc += u_reg[i * 4 + 0] * v.x + u_reg[i * 4 + 1] * v.y +
               u_reg[i * 4 + 2] * v.z + u_reg[i * 4 + 3] * v.w;
      }
      e_t[kc & 1][k * 4 + row4] = __expf(acc * 0.25f);
    }
  };

  float n_acc[4][4] = {}, d_acc[4][4] = {};
  auto accum = [&](const float4 (&pv)[4], const int4 (&pm)[4], int buf) {
#pragma unroll
    for (int j = 0; j < 4; ++j) {
      const int kk = kb + j * 16;
      float4 e4 = *(const float4*)&e_t[buf][kk * 4];
      float ev[4] = {e4.x, e4.y, e4.z, e4.w};
      const float4 v = pv[j];
      const int4 mm = pm[j];
      float mv[4], mk[4];
      mv[0] = mm.x ? v.x : 0.f; mk[0] = mm.x ? 1.f : 0.f;
      mv[1] = mm.y ? v.y : 0.f; mk[1] = mm.y ? 1.f : 0.f;
      mv[2] = mm.z ? v.z : 0.f; mk[2] = mm.z ? 1.f : 0.f;
      mv[3] = mm.w ? v.w : 0.f; mk[3] = mm.w ? 1.f : 0.f;
#pragma unroll
      for (int r = 0; r < 4; ++r)
#pragma unroll
        for (int i = 0; i < 4; ++i) {
          n_acc[r][i] += ev[r] * mv[i];
          d_acc[r][i] += ev[r] * mk[i];
        }
    }
  };

  do_scores(0);  // writes e_t[0]; first read is after the loop's first sync

  // ---- main loop: prefetch kc+1 before the barrier, consume kc after ----
#pragma unroll
  for (int kc = 0; kc < 8; ++kc) {
    if ((kc & 1) == 0) {
      if (kc + 1 < 8) issue(kc + 1, pv1, pm1);
      __syncthreads();               // e_t[kc&1] ready; prior buf free
      if (kc + 1 < 8) do_scores(kc + 1);
      accum(pv0, pm0, 0);
    } else {
      if (kc + 1 < 8) issue(kc + 1, pv0, pm0);
      __syncthreads();
      if (kc + 1 < 8) do_scores(kc + 1);
      accum(pv1, pm1, 1);
    }
  }

  // ---- reduction: shfl kkl pairs, then LDS over the 8 waves ----
#pragma unroll
  for (int r = 0; r < 4; ++r)
#pragma unroll
    for (int i = 0; i < 4; ++i) {
      n_acc[r][i] += __shfl_xor(n_acc[r][i], 32);
      d_acc[r][i] += __shfl_xor(d_acc[r][i], 32);
    }
  if ((tid & 32) == 0) {
#pragma unroll
    for (int r = 0; r < 4; ++r) {
      float4 nn, dd;
      nn.x = n_acc[r][0]; nn.y = n_acc[r][1]; nn.z = n_acc[r][2]; nn.w = n_acc[r][3];
      dd.x = d_acc[r][0]; dd.y = d_acc[r][1]; dd.z = d_acc[r][2]; dd.w = d_acc[r][3];
      *(float4*)&red_n[((r * 8 + w) * 32 + cq) * 4] = nn;
      *(float4*)&red_d[((r * 8 + w) * 32 + cq) * 4] = dd;
    }
  }
  __syncthreads();
  if (tid < 128) {
    const int r = tid >> 5, c = tid & 31;
    float4 ns = {0.f, 0.f, 0.f, 0.f}, ds = {0.f, 0.f, 0.f, 0.f};
#pragma unroll
    for (int g = 0; g < 8; ++g) {
      float4 nn = *(const float4*)&red_n[((r * 8 + g) * 32 + c) * 4];
      float4 dd = *(const float4*)&red_d[((r * 8 + g) * 32 + c) * 4];
      ns.x += nn.x; ns.y += nn.y; ns.z += nn.z; ns.w += nn.w;
      ds.x += dd.x; ds.y += dd.y; ds.z += dd.z; ds.w += dd.w;
    }
    const int h = r >> 1, q = r & 1;
    float4 x;
    x.x = ns.x / ds.x; x.y = ns.y / ds.y; x.z = ns.z / ds.z; x.w = ns.w / ds.w;
    *(float4*)&x_l[q * 264 + h * 128 + c * 4] = x;
  }
  __syncthreads();

  // ---- P4: out = x @ Wout + bout. Wout straight from global (L2/L3-hot) ----
  {
    const int g = tid >> 4, oc4 = tid & 15;  // g: 32 K-groups of 8
    float4 a0 = {0.f, 0.f, 0.f, 0.f}, a1 = {0.f, 0.f, 0.f, 0.f};
#pragma unroll
    for (int j = 0; j < 8; ++j) {
      const int k = g * 8 + j;
      float4 w4 = *(const float4*)&Wout[k * 64 + oc4 * 4];
      const float xv0 = x_l[k];
      const float xv1 = x_l[264 + k];
      a0.x += xv0 * w4.x; a0.y += xv0 * w4.y; a0.z += xv0 * w4.z; a0.w += xv0 * w4.w;
      a1.x += xv1 * w4.x; a1.y += xv1 * w4.y; a1.z += xv1 * w4.z; a1.w += xv1 * w4.w;
    }
    *(float4*)&p4[(g * 2 + 0) * 64 + oc4 * 4] = a0;
    *(float4*)&p4[(g * 2 + 1) * 64 + oc4 * 4] = a1;
  }
  __syncthreads();
  if (tid < 128) {
    const int q = tid >> 6, oc = tid & 63;
    float acc = bout[oc];
#pragma unroll
    for (int g = 0; g < 32; ++g) acc += p4[(g * 2 + q) * 64 + oc];
    out[(size_t)(b * 64 + q0 + q) * 64 + oc] = acc;
  }
}

extern "C" void kernel_launch(void* const* d_in, const int* in_sizes, int n_in,
                              void* d_out, int out_size, void* d_ws, size_t ws_size,
                              hipStream_t stream) {
  const float* query = (const float*)d_in[0];
  const float* key   = (const float*)d_in[1];
  const float* value = (const float*)d_in[2];
  const int*   mask  = (const int*)d_in[3];
  const float* Wq    = (const float*)d_in[4];
  const float* bq    = (const float*)d_in[5];
  const float* Wk    = (const float*)d_in[6];
  const float* bk    = (const float*)d_in[7];
  const float* Wout  = (const float*)d_in[8];
  const float* bout  = (const float*)d_in[9];
  float* out = (float*)d_out;

  fld_fused<<<NBLK, 512, 0, stream>>>(query, key, value, mask, Wq, bq, Wk, bk,
                                      Wout, bout, out);
}

// Round 9
// 135.745 us; speedup vs baseline: 1.0038x; 1.0038x over previous
//
#include <hip/hip_runtime.h>
#include <hip/hip_bf16.h>

// FLDAttention — single kernel, no grid barriers, no global scratch.
//
// Algebra:
//   scores are channel-independent; mask enters as 0/1 weights; with
//   x = num/den the softmax row-max cancels (scores ~N(0,0.08), exp safe):
//     e[h,q,k] = exp((key[k,:]·u[h,q,:] + beta[h,q]) / 4)
//     u[h,q,t] = sum_c Wk[t, h*16+c] * qproj[q, h*16+c]   (k-projection folded
//     beta[h,q] = sum_c bk[h*16+c]  * qproj[q, h*16+c]     into the q side!)
//     x[h,q,c] = (sum_k e*m[k,c]*v[k,c]) / (sum_k e*m[k,c])
//
// Schedule: value/mask register-prefetched one 64-k chunk ahead in 16 NAMED
// float4/int4 variables (no arrays/lambdas -> no scratch; round-7 lesson:
// compiler capped VGPR at 128 for occupancy and spilled 126 MB/dispatch).
// __launch_bounds__(512,2) permits 256 VGPR — 1 block/CU is all we get
// anyway. Chunk-0 loads issue at kernel entry under the prologue; score
// work alternates wave-halves (even chunks: waves 0-3, odd: 4-7).
//
// Block = (b = blk&7, 2 q-rows). 512 threads (8 waves). 256 blocks = 1/CU.

#define NBLK 256

__global__ __launch_bounds__(512, 2) void fld_fused(
    const float* __restrict__ query, const float* __restrict__ key,
    const float* __restrict__ value, const int* __restrict__ mask,
    const float* __restrict__ Wq, const float* __restrict__ bq,
    const float* __restrict__ Wk, const float* __restrict__ bk,
    const float* __restrict__ Wout, const float* __restrict__ bout,
    float* __restrict__ out) {
  __shared__ float q_l[2 * 36];            // projected q rows
  __shared__ float u_l[4 * 36];            // folded score vectors [row][32]
  __shared__ float beta_l[4];
  __shared__ float e_t[2][64 * 4];         // [buf][k][row] exp(scores), transposed
  __shared__ float red_n[4 * 8 * 32 * 4];  // [row][w][cq][4ch] partial numerators
  __shared__ float red_d[4 * 8 * 32 * 4];  // partial denominators
  __shared__ float x_l[2 * 264];           // [q][h*128+c]
  __shared__ float p4[64 * 64];            // [g*2+q][oc] out-GEMM partials

  const int tid = threadIdx.x;
  const int blk = blockIdx.x;
  const int b = blk & 7;
  const int q0 = (blk >> 3) * 2;

  const int w = tid >> 6, kkl = (tid >> 5) & 1, cq = tid & 31;
  const int kb = w * 2 + kkl;
  const int row4 = (tid >> 6) & 3;         // score row for this thread
  const float4* vb = (const float4*)value + (size_t)b * 512 * 32;
  const int4* mb = (const int4*)mask + (size_t)b * 512 * 32;

  float4 vA0, vA1, vA2, vA3, vB0, vB1, vB2, vB3;
  int4 mA0, mA1, mA2, mA3, mB0, mB1, mB2, mB3;

#define ISSUE(V0, V1, V2, V3, M0, M1, M2, M3, kc)      \
  do {                                                 \
    V0 = vb[((kc) * 64 + kb + 0) * 32 + cq];           \
    M0 = mb[((kc) * 64 + kb + 0) * 32 + cq];           \
    V1 = vb[((kc) * 64 + kb + 16) * 32 + cq];          \
    M1 = mb[((kc) * 64 + kb + 16) * 32 + cq];          \
    V2 = vb[((kc) * 64 + kb + 32) * 32 + cq];          \
    M2 = mb[((kc) * 64 + kb + 32) * 32 + cq];          \
    V3 = vb[((kc) * 64 + kb + 48) * 32 + cq];          \
    M3 = mb[((kc) * 64 + kb + 48) * 32 + cq];          \
  } while (0)

#define DO_SCORES(kc)                                                   \
  do {                                                                  \
    if ((tid >> 8) == ((kc) & 1)) {                                     \
      const int k_ = tid & 63;                                          \
      const float* krow_ = key + (size_t)(b * 512 + (kc) * 64 + k_) * 32; \
      float acc_ = beta_reg;                                            \
      _Pragma("unroll") for (int i_ = 0; i_ < 8; ++i_) {                \
        float4 v_ = *(const float4*)&krow_[i_ * 4];                     \
        acc_ += u_reg[i_ * 4 + 0] * v_.x + u_reg[i_ * 4 + 1] * v_.y +   \
                u_reg[i_ * 4 + 2] * v_.z + u_reg[i_ * 4 + 3] * v_.w;    \
      }                                                                 \
      e_t[(kc) & 1][k_ * 4 + row4] = __expf(acc_ * 0.25f);              \
    }                                                                   \
  } while (0)

#define ACC1(V, M, jj, ebuf)                                            \
  do {                                                                  \
    float4 e4_ = *(const float4*)&e_t[ebuf][(kb + (jj) * 16) * 4];      \
    float ev_[4] = {e4_.x, e4_.y, e4_.z, e4_.w};                        \
    float mv_[4], mk_[4];                                               \
    mv_[0] = M.x ? V.x : 0.f; mk_[0] = M.x ? 1.f : 0.f;                 \
    mv_[1] = M.y ? V.y : 0.f; mk_[1] = M.y ? 1.f : 0.f;                 \
    mv_[2] = M.z ? V.z : 0.f; mk_[2] = M.z ? 1.f : 0.f;                 \
    mv_[3] = M.w ? V.w : 0.f; mk_[3] = M.w ? 1.f : 0.f;                 \
    _Pragma("unroll") for (int r_ = 0; r_ < 4; ++r_)                    \
      _Pragma("unroll") for (int i_ = 0; i_ < 4; ++i_) {                \
        n_acc[r_][i_] += ev_[r_] * mv_[i_];                             \
        d_acc[r_][i_] += ev_[r_] * mk_[i_];                             \
      }                                                                 \
  } while (0)

#define ACCUM(V0, V1, V2, V3, M0, M1, M2, M3, ebuf) \
  do {                                              \
    ACC1(V0, M0, 0, ebuf);                          \
    ACC1(V1, M1, 1, ebuf);                          \
    ACC1(V2, M2, 2, ebuf);                          \
    ACC1(V3, M3, 3, ebuf);                          \
  } while (0)

  // chunk-0 loads in flight under the whole prologue
  ISSUE(vA0, vA1, vA2, vA3, mA0, mA1, mA2, mA3, 0);

  // ---- prologue: q projection (row encoding: row = h*2 + q) ----
  if (tid < 64) {
    const int q = tid >> 5, c = tid & 31;
    const float* qrow = query + (size_t)(b * 64 + q0 + q) * 32;
    float acc = bq[c];
#pragma unroll
    for (int t = 0; t < 32; ++t) acc += qrow[t] * Wq[t * 32 + c];
    q_l[q * 36 + c] = acc;
  }
  __syncthreads();
  if (tid < 128) {
    const int row = tid >> 5, t = tid & 31;
    const int h = row >> 1, q = row & 1;
    float acc = 0.f;
#pragma unroll
    for (int c = 0; c < 16; ++c)
      acc += Wk[t * 32 + h * 16 + c] * q_l[q * 36 + h * 16 + c];
    u_l[row * 36 + t] = acc;
  } else if (tid < 132) {
    const int row = tid - 128;
    const int h = row >> 1, q = row & 1;
    float acc = 0.f;
#pragma unroll
    for (int c = 0; c < 16; ++c) acc += bk[h * 16 + c] * q_l[q * 36 + h * 16 + c];
    beta_l[row] = acc;
  }
  __syncthreads();

  // ---- all threads hold u for their row in registers ----
  float u_reg[32];
#pragma unroll
  for (int i = 0; i < 8; ++i) {
    float4 v = *(const float4*)&u_l[row4 * 36 + i * 4];
    u_reg[i * 4 + 0] = v.x; u_reg[i * 4 + 1] = v.y;
    u_reg[i * 4 + 2] = v.z; u_reg[i * 4 + 3] = v.w;
  }
  const float beta_reg = beta_l[row4];

  float n_acc[4][4] = {}, d_acc[4][4] = {};

  DO_SCORES(0);  // writes e_t[0]; first read after the first loop sync

  // ---- 8-chunk pipeline: issue kc+1 before barrier, consume kc after ----
  ISSUE(vB0, vB1, vB2, vB3, mB0, mB1, mB2, mB3, 1);
  __syncthreads();
  DO_SCORES(1);
  ACCUM(vA0, vA1, vA2, vA3, mA0, mA1, mA2, mA3, 0);

  ISSUE(vA0, vA1, vA2, vA3, mA0, mA1, mA2, mA3, 2);
  __syncthreads();
  DO_SCORES(2);
  ACCUM(vB0, vB1, vB2, vB3, mB0, mB1, mB2, mB3, 1);

  ISSUE(vB0, vB1, vB2, vB3, mB0, mB1, mB2, mB3, 3);
  __syncthreads();
  DO_SCORES(3);
  ACCUM(vA0, vA1, vA2, vA3, mA0, mA1, mA2, mA3, 0);

  ISSUE(vA0, vA1, vA2, vA3, mA0, mA1, mA2, mA3, 4);
  __syncthreads();
  DO_SCORES(4);
  ACCUM(vB0, vB1, vB2, vB3, mB0, mB1, mB2, mB3, 1);

  ISSUE(vB0, vB1, vB2, vB3, mB0, mB1, mB2, mB3, 5);
  __syncthreads();
  DO_SCORES(5);
  ACCUM(vA0, vA1, vA2, vA3, mA0, mA1, mA2, mA3, 0);

  ISSUE(vA0, vA1, vA2, vA3, mA0, mA1, mA2, mA3, 6);
  __syncthreads();
  DO_SCORES(6);
  ACCUM(vB0, vB1, vB2, vB3, mB0, mB1, mB2, mB3, 1);

  ISSUE(vB0, vB1, vB2, vB3, mB0, mB1, mB2, mB3, 7);
  __syncthreads();
  DO_SCORES(7);
  ACCUM(vA0, vA1, vA2, vA3, mA0, mA1, mA2, mA3, 0);

  __syncthreads();
  ACCUM(vB0, vB1, vB2, vB3, mB0, mB1, mB2, mB3, 1);

  // ---- reduction: shfl kkl pairs, then LDS over the 8 waves ----
#pragma unroll
  for (int r = 0; r < 4; ++r)
#pragma unroll
    for (int i = 0; i < 4; ++i) {
      n_acc[r][i] += __shfl_xor(n_acc[r][i], 32);
      d_acc[r][i] += __shfl_xor(d_acc[r][i], 32);
    }
  if ((tid & 32) == 0) {
#pragma unroll
    for (int r = 0; r < 4; ++r) {
      float4 nn, dd;
      nn.x = n_acc[r][0]; nn.y = n_acc[r][1]; nn.z = n_acc[r][2]; nn.w = n_acc[r][3];
      dd.x = d_acc[r][0]; dd.y = d_acc[r][1]; dd.z = d_acc[r][2]; dd.w = d_acc[r][3];
      *(float4*)&red_n[((r * 8 + w) * 32 + cq) * 4] = nn;
      *(float4*)&red_d[((r * 8 + w) * 32 + cq) * 4] = dd;
    }
  }
  __syncthreads();
  if (tid < 128) {
    const int r = tid >> 5, c = tid & 31;
    float4 ns = {0.f, 0.f, 0.f, 0.f}, ds = {0.f, 0.f, 0.f, 0.f};
#pragma unroll
    for (int g = 0; g < 8; ++g) {
      float4 nn = *(const float4*)&red_n[((r * 8 + g) * 32 + c) * 4];
      float4 dd = *(const float4*)&red_d[((r * 8 + g) * 32 + c) * 4];
      ns.x += nn.x; ns.y += nn.y; ns.z += nn.z; ns.w += nn.w;
      ds.x += dd.x; ds.y += dd.y; ds.z += dd.z; ds.w += dd.w;
    }
    const int h = r >> 1, q = r & 1;
    float4 x;
    x.x = ns.x / ds.x; x.y = ns.y / ds.y; x.z = ns.z / ds.z; x.w = ns.w / ds.w;
    *(float4*)&x_l[q * 264 + h * 128 + c * 4] = x;
  }
  __syncthreads();

  // ---- P4: out = x @ Wout + bout. Wout straight from global (L2/L3-hot) ----
  {
    const int g = tid >> 4, oc4 = tid & 15;  // g: 32 K-groups of 8
    float4 a0 = {0.f, 0.f, 0.f, 0.f}, a1 = {0.f, 0.f, 0.f, 0.f};
#pragma unroll
    for (int j = 0; j < 8; ++j) {
      const int k = g * 8 + j;
      float4 w4 = *(const float4*)&Wout[k * 64 + oc4 * 4];
      const float xv0 = x_l[k];
      const float xv1 = x_l[264 + k];
      a0.x += xv0 * w4.x; a0.y += xv0 * w4.y; a0.z += xv0 * w4.z; a0.w += xv0 * w4.w;
      a1.x += xv1 * w4.x; a1.y += xv1 * w4.y; a1.z += xv1 * w4.z; a1.w += xv1 * w4.w;
    }
    *(float4*)&p4[(g * 2 + 0) * 64 + oc4 * 4] = a0;
    *(float4*)&p4[(g * 2 + 1) * 64 + oc4 * 4] = a1;
  }
  __syncthreads();
  if (tid < 128) {
    const int q = tid >> 6, oc = tid & 63;
    float acc = bout[oc];
#pragma unroll
    for (int g = 0; g < 32; ++g) acc += p4[(g * 2 + q) * 64 + oc];
    out[(size_t)(b * 64 + q0 + q) * 64 + oc] = acc;
  }
}

extern "C" void kernel_launch(void* const* d_in, const int* in_sizes, int n_in,
                              void* d_out, int out_size, void* d_ws, size_t ws_size,
                              hipStream_t stream) {
  const float* query = (const float*)d_in[0];
  const float* key   = (const float*)d_in[1];
  const float* value = (const float*)d_in[2];
  const int*   mask  = (const int*)d_in[3];
  const float* Wq    = (const float*)d_in[4];
  const float* bq    = (const float*)d_in[5];
  const float* Wk    = (const float*)d_in[6];
  const float* bk    = (const float*)d_in[7];
  const float* Wout  = (const float*)d_in[8];
  const float* bout  = (const float*)d_in[9];
  float* out = (float*)d_out;

  fld_fused<<<NBLK, 512, 0, stream>>>(query, key, value, mask, Wq, bq, Wk, bk,
                                      Wout, bout, out);
}

// Round 12
// 83.885 us; speedup vs baseline: 1.6245x; 1.6182x over previous
//
#include <hip/hip_runtime.h>
#include <hip/hip_bf16.h>

// FLDAttention — single kernel, ONE main barrier, no global scratch.
//
// Algebra:
//   scores are channel-independent; mask enters as 0/1 weights; with
//   x = num/den the softmax row-max cancels (scores ~N(0,0.08), exp safe):
//     e[h,q,k] = exp((key[k,:]·u[h,q,:] + beta[h,q]) / 4)
//     u[h,q,t] = sum_c Wk[t, h*16+c] * qproj[q, h*16+c]   (k-projection folded
//     beta[h,q] = sum_c bk[h*16+c]  * qproj[q, h*16+c]     into the q side!)
//     x[h,q,c] = (sum_k e*m[k,c]*v[k,c]) / (sum_k e*m[k,c])
//
// Round-9 lessons: (1) __syncthreads() drains vmcnt(0) -> register prefetch
// across barriers NEVER overlaps; (2) compiler pins VGPR at 128 and spills
// big named-register pipelines (FETCH/WRITE exploded to 126 MB of scratch).
// Fix: compute ALL 512 scores in one phase (thread k -> e_t[k][0..3]), one
// barrier, then a BARRIER-FREE streaming n/d loop the compiler can pipeline
// with its own vmcnt(N) counting. Live state ~90 VGPR -> no spill.
//
// Block = (b = blk&7, 2 q-rows). 512 threads (8 waves). 256 blocks = 1/CU.

#define NBLK 256

__global__ __launch_bounds__(512) void fld_fused(
    const float* __restrict__ query, const float* __restrict__ key,
    const float* __restrict__ value, const int* __restrict__ mask,
    const float* __restrict__ Wq, const float* __restrict__ bq,
    const float* __restrict__ Wk, const float* __restrict__ bk,
    const float* __restrict__ Wout, const float* __restrict__ bout,
    float* __restrict__ out) {
  __shared__ float q_l[2 * 36];            // projected q rows
  __shared__ float u_l[4 * 36];            // folded score vectors [row][32]
  __shared__ float beta_l[4];
  __shared__ float e_t[512 * 4];           // [k][row] exp(scores) — 8 KB
  __shared__ float red_n[4 * 8 * 32 * 4];  // [row][w][cq][4ch] partial num
  __shared__ float red_d[4 * 8 * 32 * 4];  // partial den
  __shared__ float x_l[2 * 264];           // [q][h*128+c]
  __shared__ float p4[64 * 64];            // [g*2+q][oc] out-GEMM partials

  const int tid = threadIdx.x;
  const int blk = blockIdx.x;
  const int b = blk & 7;
  const int q0 = (blk >> 3) * 2;

  // ---- prologue: q projection (row encoding: row = h*2 + q) ----
  if (tid < 64) {
    const int q = tid >> 5, c = tid & 31;
    const float* qrow = query + (size_t)(b * 64 + q0 + q) * 32;
    float acc = bq[c];
#pragma unroll
    for (int t = 0; t < 32; ++t) acc += qrow[t] * Wq[t * 32 + c];
    q_l[q * 36 + c] = acc;
  }
  __syncthreads();
  if (tid < 128) {
    const int row = tid >> 5, t = tid & 31;
    const int h = row >> 1, q = row & 1;
    float acc = 0.f;
#pragma unroll
    for (int c = 0; c < 16; ++c)
      acc += Wk[t * 32 + h * 16 + c] * q_l[q * 36 + h * 16 + c];
    u_l[row * 36 + t] = acc;
  } else if (tid < 132) {
    const int row = tid - 128;
    const int h = row >> 1, q = row & 1;
    float acc = 0.f;
#pragma unroll
    for (int c = 0; c < 16; ++c) acc += bk[h * 16 + c] * q_l[q * 36 + h * 16 + c];
    beta_l[row] = acc;
  }
  __syncthreads();

  // ---- Phase A: full score table. thread = k (512 of them) ----
  {
    const int k = tid;
    const float* krow = key + (size_t)(b * 512 + k) * 32;
    const float4 k0 = *(const float4*)&krow[0];
    const float4 k1 = *(const float4*)&krow[4];
    const float4 k2 = *(const float4*)&krow[8];
    const float4 k3 = *(const float4*)&krow[12];
    const float4 k4 = *(const float4*)&krow[16];
    const float4 k5 = *(const float4*)&krow[20];
    const float4 k6 = *(const float4*)&krow[24];
    const float4 k7 = *(const float4*)&krow[28];
    float s[4];
#pragma unroll
    for (int r = 0; r < 4; ++r) {
      float acc = beta_l[r];
      const float* ur = &u_l[r * 36];
      float4 u4;
      u4 = *(const float4*)&ur[0];
      acc += u4.x * k0.x + u4.y * k0.y + u4.z * k0.z + u4.w * k0.w;
      u4 = *(const float4*)&ur[4];
      acc += u4.x * k1.x + u4.y * k1.y + u4.z * k1.z + u4.w * k1.w;
      u4 = *(const float4*)&ur[8];
      acc += u4.x * k2.x + u4.y * k2.y + u4.z * k2.z + u4.w * k2.w;
      u4 = *(const float4*)&ur[12];
      acc += u4.x * k3.x + u4.y * k3.y + u4.z * k3.z + u4.w * k3.w;
      u4 = *(const float4*)&ur[16];
      acc += u4.x * k4.x + u4.y * k4.y + u4.z * k4.z + u4.w * k4.w;
      u4 = *(const float4*)&ur[20];
      acc += u4.x * k5.x + u4.y * k5.y + u4.z * k5.z + u4.w * k5.w;
      u4 = *(const float4*)&ur[24];
      acc += u4.x * k6.x + u4.y * k6.y + u4.z * k6.z + u4.w * k6.w;
      u4 = *(const float4*)&ur[28];
      acc += u4.x * k7.x + u4.y * k7.y + u4.z * k7.z + u4.w * k7.w;
      s[r] = acc;
    }
    float4 er;
    er.x = __expf(s[0] * 0.25f);
    er.y = __expf(s[1] * 0.25f);
    er.z = __expf(s[2] * 0.25f);
    er.w = __expf(s[3] * 0.25f);
    *(float4*)&e_t[k * 4] = er;
  }
  __syncthreads();  // e_t ready — the ONLY main-path barrier

  // ---- Phase B: barrier-free n/d streaming accumulation ----
  const int w = tid >> 6, kkl = (tid >> 5) & 1, cq = tid & 31;
  const int kb = w * 2 + kkl;  // 0..15
  float n_acc[4][4] = {}, d_acc[4][4] = {};
  const float4* vb = (const float4*)value + (size_t)b * 512 * 32;
  const int4* mb = (const int4*)mask + (size_t)b * 512 * 32;

#pragma unroll 4
  for (int j = 0; j < 32; ++j) {
    const int kk = kb + j * 16;  // covers 0..511 across (kb, j)
    const float4 v = vb[kk * 32 + cq];
    const int4 mm = mb[kk * 32 + cq];
    const float4 e4 = *(const float4*)&e_t[kk * 4];
    float ev[4] = {e4.x, e4.y, e4.z, e4.w};
    float mv[4], mk[4];
    mv[0] = mm.x ? v.x : 0.f; mk[0] = mm.x ? 1.f : 0.f;
    mv[1] = mm.y ? v.y : 0.f; mk[1] = mm.y ? 1.f : 0.f;
    mv[2] = mm.z ? v.z : 0.f; mk[2] = mm.z ? 1.f : 0.f;
    mv[3] = mm.w ? v.w : 0.f; mk[3] = mm.w ? 1.f : 0.f;
#pragma unroll
    for (int r = 0; r < 4; ++r)
#pragma unroll
      for (int i = 0; i < 4; ++i) {
        n_acc[r][i] += ev[r] * mv[i];
        d_acc[r][i] += ev[r] * mk[i];
      }
  }

  // ---- reduction: shfl kkl pairs, then LDS over the 8 waves ----
#pragma unroll
  for (int r = 0; r < 4; ++r)
#pragma unroll
    for (int i = 0; i < 4; ++i) {
      n_acc[r][i] += __shfl_xor(n_acc[r][i], 32);
      d_acc[r][i] += __shfl_xor(d_acc[r][i], 32);
    }
  if ((tid & 32) == 0) {
#pragma unroll
    for (int r = 0; r < 4; ++r) {
      float4 nn, dd;
      nn.x = n_acc[r][0]; nn.y = n_acc[r][1]; nn.z = n_acc[r][2]; nn.w = n_acc[r][3];
      dd.x = d_acc[r][0]; dd.y = d_acc[r][1]; dd.z = d_acc[r][2]; dd.w = d_acc[r][3];
      *(float4*)&red_n[((r * 8 + w) * 32 + cq) * 4] = nn;
      *(float4*)&red_d[((r * 8 + w) * 32 + cq) * 4] = dd;
    }
  }
  __syncthreads();
  if (tid < 128) {
    const int r = tid >> 5, c = tid & 31;
    float4 ns = {0.f, 0.f, 0.f, 0.f}, ds = {0.f, 0.f, 0.f, 0.f};
#pragma unroll
    for (int g = 0; g < 8; ++g) {
      float4 nn = *(const float4*)&red_n[((r * 8 + g) * 32 + c) * 4];
      float4 dd = *(const float4*)&red_d[((r * 8 + g) * 32 + c) * 4];
      ns.x += nn.x; ns.y += nn.y; ns.z += nn.z; ns.w += nn.w;
      ds.x += dd.x; ds.y += dd.y; ds.z += dd.z; ds.w += dd.w;
    }
    const int h = r >> 1, q = r & 1;
    float4 x;
    x.x = ns.x / ds.x; x.y = ns.y / ds.y; x.z = ns.z / ds.z; x.w = ns.w / ds.w;
    *(float4*)&x_l[q * 264 + h * 128 + c * 4] = x;
  }
  __syncthreads();

  // ---- P4: out = x @ Wout + bout. Wout straight from global (L2/L3-hot) ----
  {
    const int g = tid >> 4, oc4 = tid & 15;  // g: 32 K-groups of 8
    float4 a0 = {0.f, 0.f, 0.f, 0.f}, a1 = {0.f, 0.f, 0.f, 0.f};
#pragma unroll
    for (int j = 0; j < 8; ++j) {
      const int k = g * 8 + j;
      float4 w4 = *(const float4*)&Wout[k * 64 + oc4 * 4];
      const float xv0 = x_l[k];
      const float xv1 = x_l[264 + k];
      a0.x += xv0 * w4.x; a0.y += xv0 * w4.y; a0.z += xv0 * w4.z; a0.w += xv0 * w4.w;
      a1.x += xv1 * w4.x; a1.y += xv1 * w4.y; a1.z += xv1 * w4.z; a1.w += xv1 * w4.w;
    }
    *(float4*)&p4[(g * 2 + 0) * 64 + oc4 * 4] = a0;
    *(float4*)&p4[(g * 2 + 1) * 64 + oc4 * 4] = a1;
  }
  __syncthreads();
  if (tid < 128) {
    const int q = tid >> 6, oc = tid & 63;
    float acc = bout[oc];
#pragma unroll
    for (int g = 0; g < 32; ++g) acc += p4[(g * 2 + q) * 64 + oc];
    out[(size_t)(b * 64 + q0 + q) * 64 + oc] = acc;
  }
}

extern "C" void kernel_launch(void* const* d_in, const int* in_sizes, int n_in,
                              void* d_out, int out_size, void* d_ws, size_t ws_size,
                              hipStream_t stream) {
  const float* query = (const float*)d_in[0];
  const float* key   = (const float*)d_in[1];
  const float* value = (const float*)d_in[2];
  const int*   mask  = (const int*)d_in[3];
  const float* Wq    = (const float*)d_in[4];
  const float* bq    = (const float*)d_in[5];
  const float* Wk    = (const float*)d_in[6];
  const float* bk    = (const float*)d_in[7];
  const float* Wout  = (const float*)d_in[8];
  const float* bout  = (const float*)d_in[9];
  float* out = (float*)d_out;

  fld_fused<<<NBLK, 512, 0, stream>>>(query, key, value, mask, Wq, bq, Wk, bk,
                                      Wout, bout, out);
}